// Round 4
// baseline (334.714 us; speedup 1.0000x reference)
//
#include <hip/hip_runtime.h>
#include <stdint.h>

// Bilinear: out[b,i,j,k] = sum_{p,q} x1[b,i,p] W[k,p,q] x2[b,j,q] + bias[k]
// B=8, L=256, P=Q=512, K=64.
//
//  - pre-convert W/x1/x2 -> bf16 into ws head (36 MiB)
//  - Stage A: S[(b,j),(k,p)] = sum_q X2b[(b,j),q] * Wb[(k,p),q]   (S bf16)
//  - Stage B: out[b,i,(j,k)] = sum_p X1b[i,p] * S_b[(j,k),p] + bias[k]
//
// GEMM geometry (R3, resubmitted R4 after infra-side container failure;
// kernel re-audited: FIFO invariant, barrier safety, OOB, LDS budget all
// verified by hand-trace): 256x128 tile, BK=64, 8 waves as 4M x 2N ->
// per-wave 64x64 output (acc 64 VGPR), all B-frags held across the K-tile
// (no LDS re-reads; per-CU LDS read traffic halved vs R2's 2Mx4N quadrant
// schedule). ONE barrier per K-tile: reads hit buf cur, writes hit buf nxt
// -> only boundary needs lgkmcnt(0)+s_barrier (R2 had 8 barriers/K-tile ->
// lockstep stall was ~3x MFMA time). Reg-staged (NO global_load_lds -
// diverged under graph replay in a prior session), 2-slot load FIFO issued
// 2 K-tiles ahead, vmcnt(3) counted waits (never drained in steady state).
// T2 XOR swizzle (conflicts=0, proven), T1 bijective XCD swizzle m-minor
// (FETCH 164->50 MB, proven), setprio around MFMA clusters, j-inner
// epilogue (WRITE_SIZE 321->133 MB, proven).

typedef __bf16 bf16x8 __attribute__((ext_vector_type(8)));
typedef float  f32x4  __attribute__((ext_vector_type(4)));

#define KDIM 512
#define BM 256
#define BN 128
#define BK 64
#define ABYTES 32768            // 256 rows x 128 B
#define BBYTES 16384            // 128 rows x 128 B
#define BUFB   49152            // bytes per double-buffer half

__global__ __launch_bounds__(256) void f32_to_bf16_kernel(
    const float* __restrict__ in, __bf16* __restrict__ out, long n8)
{
    for (long i = blockIdx.x * 256L + threadIdx.x; i < n8; i += gridDim.x * 256L) {
        f32x4 a = *(const f32x4*)(in + i * 8);
        f32x4 b = *(const f32x4*)(in + i * 8 + 4);
        bf16x8 o;
        o[0]=(__bf16)a[0]; o[1]=(__bf16)a[1]; o[2]=(__bf16)a[2]; o[3]=(__bf16)a[3];
        o[4]=(__bf16)b[0]; o[5]=(__bf16)b[1]; o[6]=(__bf16)b[2]; o[7]=(__bf16)b[3];
        *(bf16x8*)(out + i * 8) = o;
    }
}

// ---- schedule primitives ----
#define VMW(N) do { \
    asm volatile("s_waitcnt vmcnt(" #N ")" ::: "memory"); \
    __builtin_amdgcn_sched_barrier(0); } while (0)
#define LGKM0() do { \
    asm volatile("s_waitcnt lgkmcnt(0)" ::: "memory"); \
    __builtin_amdgcn_sched_barrier(0); } while (0)
#define SB() __builtin_amdgcn_sched_barrier(0)

// ---- staging: per thread 6 loads/K-tile in 2 groups of 3 ----
// g0 = A rows {r, r+64}  + B row r      ; g1 = A rows {r+128, r+192} + B row r+64
#define LG0(kt) do { \
    e0 = *(const bf16x8*)(gA + (kt) * BK); \
    e1 = *(const bf16x8*)(gA + 64L * KDIM + (kt) * BK); \
    e2 = *(const bf16x8*)(gB + (kt) * BK); } while (0)
#define LG1(kt) do { \
    o0 = *(const bf16x8*)(gA + 128L * KDIM + (kt) * BK); \
    o1 = *(const bf16x8*)(gA + 192L * KDIM + (kt) * BK); \
    o2 = *(const bf16x8*)(gB + 64L * KDIM + (kt) * BK); } while (0)
#define WG0(bi) do { char* w_ = lds + (bi) * BUFB; \
    *(bf16x8*)(w_ + sbw)              = e0; \
    *(bf16x8*)(w_ + 8192 + sbw)       = e1; \
    *(bf16x8*)(w_ + ABYTES + sbw)     = e2; } while (0)
#define WG1(bi) do { char* w_ = lds + (bi) * BUFB; \
    *(bf16x8*)(w_ + 16384 + sbw)          = o0; \
    *(bf16x8*)(w_ + 24576 + sbw)          = o1; \
    *(bf16x8*)(w_ + ABYTES + 8192 + sbw)  = o2; } while (0)

// ---- fragment reads (XOR-swizzled) ----
#define RDB(bi) do { const char* b_ = lds + (bi) * BUFB + ABYTES; \
    _Pragma("unroll") for (int j_ = 0; j_ < 4; ++j_) { \
        const int ro_ = (wn * 64 + j_ * 16 + lcol) * 128; \
        bfr[j_][0] = *(const bf16x8*)(b_ + ro_ + ko0); \
        bfr[j_][1] = *(const bf16x8*)(b_ + ro_ + ko1); } } while (0)
#define RDA(bi, ih) do { const char* a_ = lds + (bi) * BUFB; \
    _Pragma("unroll") for (int i_ = 0; i_ < 2; ++i_) { \
        const int ro_ = (wm * 64 + ((ih) * 2 + i_) * 16 + lcol) * 128; \
        af[i_][0] = *(const bf16x8*)(a_ + ro_ + ko0); \
        af[i_][1] = *(const bf16x8*)(a_ + ro_ + ko1); } } while (0)
#define MF(ih) do { \
    _Pragma("unroll") for (int i_ = 0; i_ < 2; ++i_) \
    _Pragma("unroll") for (int j_ = 0; j_ < 4; ++j_) \
    _Pragma("unroll") for (int k_ = 0; k_ < 2; ++k_) \
        acc[(ih) * 2 + i_][j_] = __builtin_amdgcn_mfma_f32_16x16x32_bf16( \
            af[i_][k_], bfr[j_][k_], acc[(ih) * 2 + i_][j_], 0, 0, 0); } while (0)

template <typename OutT>
__global__ __launch_bounds__(512, 2) void gemm_nt_256x128(
    const __bf16* __restrict__ A,    // [M x 512] row-major
    const __bf16* __restrict__ B,    // [N x 512] row-major  (C = A * B^T)
    OutT* __restrict__ C,            // [M x ldc] row-major
    const float* __restrict__ bias,  // nullptr, or [64]: adds bias[col & 63]
    int ldc, int mtiles,             // m-tiles per z-slice (m-minor tile order)
    long sA, long sB, long sC)       // per-z strides (elements)
{
    __shared__ __align__(16) char lds[2 * BUFB];   // 96 KiB

    const int tid  = threadIdx.x;
    const int lane = tid & 63;
    const int wave = tid >> 6;        // 0..7
    const int wm   = wave & 3;        // 4 M-waves (64 rows each)
    const int wn   = wave >> 2;       // 2 N-waves (64 cols each)
    const int lcol = lane & 15;
    const int krow = (lane >> 4) & 3;
    const int rsw  = (lcol & 7) << 4;
    const int ko0  = (krow * 16) ^ rsw;
    const int ko1  = (64 + krow * 16) ^ rsw;

    // Bijective XCD swizzle over the flattened grid (m204 formula).
    long flat = (long)blockIdx.z * gridDim.x + blockIdx.x;
    long nwg  = (long)gridDim.x * gridDim.z;
    long q = nwg >> 3, r8 = nwg & 7;
    long xcd = flat & 7, lo = flat >> 3;
    long sz = (xcd < r8 ? xcd * (q + 1) : r8 * (q + 1) + (xcd - r8) * q) + lo;
    const int z   = (int)(sz / (long)gridDim.x);
    const int rem = (int)(sz % (long)gridDim.x);
    const int n0 = (rem / mtiles) * BN;   // m-minor: same n-tile (W panel)
    const int m0 = (rem % mtiles) * BM;   // stays on one XCD's L2

    A += (long)z * sA + (long)m0 * KDIM;
    B += (long)z * sB + (long)n0 * KDIM;
    C += (long)z * sC;

    // Staging indices: thread covers A rows r+{0,64,128,192}, B rows r+{0,64}
    // at 16-B column c8.  XOR-swizzled LDS byte offset (same for all row+64k).
    const int r  = tid >> 3;
    const int c8 = tid & 7;
    const int sbw = r * 128 + ((c8 * 16) ^ ((r & 7) << 4));
    const __bf16* gA = A + (long)r * KDIM + c8 * 8;
    const __bf16* gB = B + (long)r * KDIM + c8 * 8;

    bf16x8 e0, e1, e2, o0, o1, o2;    // 2-slot load FIFO (named -> registers)
    f32x4 acc[4][4] = {};

    // ---- prologue: tile0 -> buf0, tile1's 6 loads left in flight ----
    LG0(0); LG1(0);
    VMW(3); WG0(0); LG0(1);
    VMW(3); WG1(0); LG1(1);
    LGKM0();
    __builtin_amdgcn_s_barrier(); SB();

    // ---- main loop: tiles 0..5, write t+1 -> nxt, issue t+2 ----
#pragma unroll
    for (int t = 0; t < 6; ++t) {
        const int cur = t & 1, nxt = cur ^ 1;
        bf16x8 bfr[4][2], af[2][2];
        RDB(cur); RDA(cur, 0);
        VMW(3); WG0(nxt); LG0(t + 2); SB();
        __builtin_amdgcn_s_setprio(1); MF(0); __builtin_amdgcn_s_setprio(0); SB();
        RDA(cur, 1);
        VMW(3); WG1(nxt); LG1(t + 2); SB();
        __builtin_amdgcn_s_setprio(1); MF(1); __builtin_amdgcn_s_setprio(0);
        LGKM0();
        __builtin_amdgcn_s_barrier(); SB();
    }
    {   // tile 6 (buf0): stage tile7 into buf1, nothing more to issue
        bf16x8 bfr[4][2], af[2][2];
        RDB(0); RDA(0, 0);
        VMW(3); WG0(1); SB();
        __builtin_amdgcn_s_setprio(1); MF(0); __builtin_amdgcn_s_setprio(0); SB();
        RDA(0, 1);
        VMW(0); WG1(1); SB();
        __builtin_amdgcn_s_setprio(1); MF(1); __builtin_amdgcn_s_setprio(0);
        LGKM0();
        __builtin_amdgcn_s_barrier(); SB();
    }
    {   // tile 7 (buf1): reads + MFMA only
        bf16x8 bfr[4][2], af[2][2];
        RDB(1); RDA(1, 0); MF(0);
        RDA(1, 1);         MF(1);
    }

    // Epilogue. C/D layout (16x16): col = lane&15, row = (lane>>4)*4 + reg.
    // j innermost: the wave completes 256 B (or 128 B bf16) lines contiguously.
    float badd[4];
#pragma unroll
    for (int j = 0; j < 4; ++j)
        badd[j] = bias ? bias[j * 16 + lcol] : 0.f;
#pragma unroll
    for (int i = 0; i < 4; ++i) {
#pragma unroll
        for (int rr = 0; rr < 4; ++rr) {
            const int row = m0 + wm * 64 + i * 16 + krow * 4 + rr;
            OutT* cp = C + (long)row * ldc + n0 + wn * 64 + lcol;
#pragma unroll
            for (int j = 0; j < 4; ++j)
                cp[j * 16] = (OutT)(acc[i][j][rr] + badd[j]);
        }
    }
}

extern "C" void kernel_launch(void* const* d_in, const int* in_sizes, int n_in,
                              void* d_out, int out_size, void* d_ws, size_t ws_size,
                              hipStream_t stream)
{
    (void)in_sizes; (void)n_in; (void)out_size;
    const float* x1f = (const float*)d_in[0];  // [8,256,512]
    const float* x2f = (const float*)d_in[1];  // [8,256,512]
    const float* Wf  = (const float*)d_in[2];  // [64,512,512]
    const float* bs  = (const float*)d_in[3];  // [64]
    float* out = (float*)d_out;                // [8,256,256,64]

    const long N_W = 64L * 512 * 512;
    const long N_X = 8L * 256 * 512;
    __bf16* Wb  = (__bf16*)d_ws;
    __bf16* x1b = Wb + N_W;
    __bf16* x2b = x1b + N_X;
    __bf16* S   = x2b + N_X;
    const size_t head_bytes = (size_t)(N_W + 2 * N_X) * sizeof(__bf16); // 36 MiB

    f32_to_bf16_kernel<<<2048, 256, 0, stream>>>(Wf,  Wb,  N_W / 8);
    f32_to_bf16_kernel<<<512,  256, 0, stream>>>(x1f, x1b, N_X / 8);
    f32_to_bf16_kernel<<<512,  256, 0, stream>>>(x2f, x2b, N_X / 8);

    const long ROWS_TOTAL = 2048;              // S rows = (b,j)
    const long ROW_ELEMS  = 32768;             // (k,p) per S row

    long rows_chunk = (ws_size > head_bytes)
        ? (long)((ws_size - head_bytes) / (ROW_ELEMS * sizeof(__bf16))) : 0;
    rows_chunk &= ~255L;
    if (rows_chunk < 256) rows_chunk = 256;
    if (rows_chunk > ROWS_TOTAL) rows_chunk = ROWS_TOTAL;

    for (long r0 = 0; r0 < ROWS_TOTAL; r0 += rows_chunk) {
        long rows = ROWS_TOTAL - r0;
        if (rows > rows_chunk) rows = rows_chunk;
        long nbc = rows >> 8;                  // whole b's this chunk
        int  mt  = (int)(rows >> 8);           // 256-row m-tiles

        // Stage A: S = X2b @ Wb^T.  M = rows, N = 32768, K = 512.
        dim3 gA((unsigned)((32768 / BN) * mt), 1, 1);
        gemm_nt_256x128<__bf16><<<gA, 512, 0, stream>>>(
            x2b + r0 * KDIM, Wb, S, nullptr, 32768, mt, 0, 0, 0);

        // Stage B: z-batched over this chunk's b's -> fp32 out (+bias).
        dim3 gB2(16384 / BN, 1, (unsigned)nbc);
        gemm_nt_256x128<float><<<gB2, 512, 0, stream>>>(
            x1b + r0 * KDIM,                   // X1_b rows
            S,                                 // S_b as [16384 x 512]
            out + r0 * 16384,                  // out_b as [256 x 16384]
            bs, 16384, 1,
            256L * KDIM, 256L * ROW_ELEMS, 256L * 16384);
    }
}